// Round 5
// baseline (258.308 us; speedup 1.0000x reference)
//
#include <hip/hip_runtime.h>

#define NN 4096

// ---------------- Phase 1: role-split partial sums ---------------------------
// One dispatch, grid (4, 1536). by in [0,512): W-role, 8 rows, reads only w.
// by in [512,1536): AH-role, 4 rows, reads alpha+hebb. Equal bytes per block
// (32 KiB). Each CU streams 1-2 matrices linearly instead of 3 interleaved.
__global__ __launch_bounds__(256, 8) void matvec_partial_kernel(
    const float* __restrict__ yin,
    const float* __restrict__ w,
    const float* __restrict__ alpha,
    const float* __restrict__ hebb,
    float* __restrict__ part1,   // 512 rows  (W partials)
    float* __restrict__ part2)   // 1024 rows (AH partials)
{
    const int col = blockIdx.x * 1024 + threadIdx.x * 4;
    const int by  = blockIdx.y;

    float4 acc = make_float4(0.f, 0.f, 0.f, 0.f);

    if (by < 512) {
        // ---- W role: 8 rows, single stream, batches of 4 rows ----
        const int r0 = by * 8;
        #pragma unroll
        for (int b = 0; b < 2; ++b) {
            float4 wv[4];
            float  yv[4];
            #pragma unroll
            for (int k = 0; k < 4; ++k) {
                const int i = r0 + b * 4 + k;
                wv[k] = *reinterpret_cast<const float4*>(w + (size_t)i * NN + col);
                yv[k] = yin[i];
            }
            #pragma unroll
            for (int k = 0; k < 4; ++k) {
                acc.x += yv[k] * wv[k].x;
                acc.y += yv[k] * wv[k].y;
                acc.z += yv[k] * wv[k].z;
                acc.w += yv[k] * wv[k].w;
            }
        }
        *reinterpret_cast<float4*>(part1 + (size_t)by * NN + col) = acc;
    } else {
        // ---- AH role: 4 rows, two streams, batches of 2 rows ----
        const int r0 = (by - 512) * 4;
        #pragma unroll
        for (int b = 0; b < 2; ++b) {
            float4 av[2], hv[2];
            float  yv[2];
            #pragma unroll
            for (int k = 0; k < 2; ++k) {
                const int i = r0 + b * 2 + k;
                const size_t off = (size_t)i * NN + col;
                av[k] = *reinterpret_cast<const float4*>(alpha + off);
                hv[k] = *reinterpret_cast<const float4*>(hebb + off);
                yv[k] = yin[i];
            }
            #pragma unroll
            for (int k = 0; k < 2; ++k) {
                acc.x += yv[k] * (av[k].x * hv[k].x);
                acc.y += yv[k] * (av[k].y * hv[k].y);
                acc.z += yv[k] * (av[k].z * hv[k].z);
                acc.w += yv[k] * (av[k].w * hv[k].w);
            }
        }
        *reinterpret_cast<float4*>(part2 + (size_t)(by - 512) * NN + col) = acc;
    }
}

// ---------------- Phase 2: reduce partials -> yout = tanh(sum + input) ------
// Grid 64 x 256. Block handles 64 columns; 4 row-slices, LDS-reduced.
// Slice sums 128 part1-rows + 256 part2-rows.
__global__ __launch_bounds__(256) void reduce_yout_kernel(
    const float* __restrict__ part1,
    const float* __restrict__ part2,
    const float* __restrict__ input,
    float* __restrict__ yout)
{
    const int tid   = threadIdx.x;
    const int j     = blockIdx.x * 64 + (tid & 63);
    const int slice = tid >> 6;           // 0..3

    float s = 0.f;
    #pragma unroll 8
    for (int kk = 0; kk < 128; ++kk)
        s += part1[(size_t)(slice * 128 + kk) * NN + j];
    #pragma unroll 8
    for (int kk = 0; kk < 256; ++kk)
        s += part2[(size_t)(slice * 256 + kk) * NN + j];

    __shared__ float sm[256];
    sm[tid] = s;
    __syncthreads();
    if (tid < 64) {
        float tot = sm[tid] + sm[tid + 64] + sm[tid + 128] + sm[tid + 192];
        yout[j] = tanhf(tot + input[j]);
    }
}

// ---------------- Phase 3: hebb' = (1-eta)*hebb + eta*outer(yin,yout) -------
// 2048 blocks x 256 threads x 8 float4 = exactly NN*NN floats. Overwrites the
// part2 scratch region (d_out + NN) completely.
__global__ __launch_bounds__(256, 8) void hebb_update_kernel(
    const float* __restrict__ hebb,
    const float* __restrict__ yin,
    const float* __restrict__ yout,
    const float* __restrict__ eta_p,
    float* __restrict__ hebb_out)
{
    const float eta = eta_p[0];
    const float om  = 1.0f - eta;
    const int tid   = blockIdx.x * 256 + threadIdx.x;   // 0..524287
    const int NT    = 2048 * 256;                       // stride in float4

    const float4 yo = reinterpret_cast<const float4*>(yout)[tid & 1023];

    #pragma unroll
    for (int half = 0; half < 2; ++half) {
        float4 hv[4];
        float  ye[4];
        #pragma unroll
        for (int it = 0; it < 4; ++it) {
            const int g = tid + (half * 4 + it) * NT;
            hv[it] = reinterpret_cast<const float4*>(hebb)[g];
            ye[it] = eta * yin[g >> 10];
        }
        #pragma unroll
        for (int it = 0; it < 4; ++it) {
            const int g = tid + (half * 4 + it) * NT;
            float4 r;
            r.x = om * hv[it].x + ye[it] * yo.x;
            r.y = om * hv[it].y + ye[it] * yo.y;
            r.z = om * hv[it].z + ye[it] * yo.z;
            r.w = om * hv[it].w + ye[it] * yo.w;
            reinterpret_cast<float4*>(hebb_out)[g] = r;
        }
    }
}

extern "C" void kernel_launch(void* const* d_in, const int* in_sizes, int n_in,
                              void* d_out, int out_size, void* d_ws, size_t ws_size,
                              hipStream_t stream) {
    const float* input = (const float*)d_in[0];
    const float* yin   = (const float*)d_in[1];
    const float* hebb  = (const float*)d_in[2];
    const float* w     = (const float*)d_in[3];
    const float* alpha = (const float*)d_in[4];
    const float* eta   = (const float*)d_in[5];

    float* out      = (float*)d_out;
    float* yout     = out;        // first NN elements
    float* hebb_out = out + NN;   // next NN*NN elements (written last by K3)

    float* part1 = (float*)d_ws;  // 512 rows = 8 MiB (ws proven >= 16 MiB)
    float* part2 = hebb_out;      // 1024 rows = 16 MiB scratch inside d_out,
                                  // fully overwritten by hebb_update afterwards

    dim3 g1(4, 1536);
    matvec_partial_kernel<<<g1, 256, 0, stream>>>(yin, w, alpha, hebb,
                                                  part1, part2);

    reduce_yout_kernel<<<NN / 64, 256, 0, stream>>>(part1, part2, input, yout);

    hebb_update_kernel<<<2048, 256, 0, stream>>>(hebb, yin, yout, eta, hebb_out);
}